// Round 9
// baseline (83.647 us; speedup 1.0000x reference)
//
#include <hip/hip_runtime.h>
#include <hip/hip_bf16.h>
#include <stdint.h>

#define NB 2
#define SEQ 4096
#define HID 256
#define NHEAD 8
#define NKVH 4
#define HDIM 32

typedef __bf16 bf16;
typedef __bf16 bf16x8 __attribute__((ext_vector_type(8)));
typedef float f32x4 __attribute__((ext_vector_type(4)));

static __device__ __forceinline__ uint16_t bfbits(float f) {
    bf16 h = (bf16)f;
    return __builtin_bit_cast(uint16_t, h);
}
static __device__ __forceinline__ uint32_t pack_bf16(float lo, float hi) {
    return (uint32_t)bfbits(lo) | ((uint32_t)bfbits(hi) << 16);
}
// raw v_exp_f32: no libm range wrapper.  exp2(-1e30) == +0 in HW.
static __device__ __forceinline__ float fexp2(float x) {
#if __has_builtin(__builtin_amdgcn_exp2f)
    return __builtin_amdgcn_exp2f(x);
#else
    float r; asm("v_exp_f32 %0, %1" : "=v"(r) : "v"(x)); return r;
#endif
}
// async global->LDS DMA, 16B per lane.  LDS dest = wave-uniform base +
// lane*16 (hardware rule); global src is per-lane.
static __device__ __forceinline__ void gld_lds16(const void* g, void* l) {
    __builtin_amdgcn_global_load_lds(
        (const __attribute__((address_space(1))) void*)g,
        (__attribute__((address_space(3))) void*)l, 16, 0, 0);
}

// ---------------------------------------------------------------------------
// Kernel 1: QKV projection + RoPE (unchanged).
// ---------------------------------------------------------------------------
__global__ __launch_bounds__(256) void qkv_proj(
    const float* __restrict__ hs, const float* __restrict__ Wq,
    const float* __restrict__ Wk, const float* __restrict__ Wv,
    bf16* __restrict__ qws, bf16* __restrict__ kws, bf16* __restrict__ vtws)
{
    __shared__ bf16 As[64][136];
    __shared__ bf16 Bs[64][136];
    const int t = threadIdx.x;
    const int wid = t >> 6, lane = t & 63;
    const int g = lane >> 4, c = lane & 15;
    const int n0 = blockIdx.x * 64;
    const int m0 = blockIdx.y * 64;

    const float* bsrc; int ro;
    if (n0 < 256)      { bsrc = Wq; ro = n0; }
    else if (n0 < 384) { bsrc = Wk; ro = n0 - 256; }
    else               { bsrc = Wv; ro = n0 - 384; }

    const f32x4 zf = {0.f, 0.f, 0.f, 0.f};
    f32x4 acc[4] = {zf, zf, zf, zf};

    const int c4 = t & 31;
    const int rb = t >> 5;

    for (int ks = 0; ks < 256; ks += 128) {
        __syncthreads();
        #pragma unroll
        for (int i = 0; i < 8; ++i) {
            int row = i * 8 + rb;
            float4 v = *(const float4*)&hs[(size_t)(m0 + row) * HID + ks + c4 * 4];
            ushort4 w; w.x = bfbits(v.x); w.y = bfbits(v.y); w.z = bfbits(v.z); w.w = bfbits(v.w);
            *(ushort4*)&As[row][c4 * 4] = w;
        }
        #pragma unroll
        for (int i = 0; i < 8; ++i) {
            int row = i * 8 + rb;
            float4 v = *(const float4*)&bsrc[(size_t)(ro + row) * HID + ks + c4 * 4];
            ushort4 w; w.x = bfbits(v.x); w.y = bfbits(v.y); w.z = bfbits(v.z); w.w = bfbits(v.w);
            *(ushort4*)&Bs[row][c4 * 4] = w;
        }
        __syncthreads();
        #pragma unroll
        for (int kk = 0; kk < 128; kk += 32) {
            bf16x8 af = *(const bf16x8*)&As[wid * 16 + c][kk + g * 8];
            #pragma unroll
            for (int nt = 0; nt < 4; ++nt) {
                bf16x8 bfr = *(const bf16x8*)&Bs[nt * 16 + c][kk + g * 8];
                acc[nt] = __builtin_amdgcn_mfma_f32_16x16x32_bf16(af, bfr, acc[nt], 0, 0, 0);
            }
        }
    }

    const float qscale = 1.4426950408889634f * 0.17677669529663687f; // log2e/sqrt(32)
    const float invf = exp2f(-0.83048202372184f * (float)c);          // 10000^(-c/16)
    #pragma unroll
    for (int r = 0; r < 4; ++r) {
        int m = m0 + wid * 16 + g * 4 + r;
        int b = m >> 12, s = m & (SEQ - 1);
        float sn, cs;
        sincosf((float)s * invf, &sn, &cs);
        if (n0 < 256) {
            #pragma unroll
            for (int np = 0; np < 4; np += 2) {
                int h = (n0 + np * 16) >> 5;
                float x1 = acc[np][r], x2 = acc[np + 1][r];
                float y1 = (x1 * cs - x2 * sn) * qscale;
                float y2 = (x2 * cs + x1 * sn) * qscale;
                size_t base = ((size_t)(b * NHEAD + h) * SEQ + s) * HDIM;
                qws[base + c] = (bf16)y1;
                qws[base + 16 + c] = (bf16)y2;
            }
        } else if (n0 < 384) {
            #pragma unroll
            for (int np = 0; np < 4; np += 2) {
                int kh = (n0 - 256 + np * 16) >> 5;
                float x1 = acc[np][r], x2 = acc[np + 1][r];
                float y1 = x1 * cs - x2 * sn;
                float y2 = x2 * cs + x1 * sn;
                size_t base = ((size_t)(b * NKVH + kh) * SEQ + s) * HDIM;
                kws[base + c] = (bf16)y1;
                kws[base + 16 + c] = (bf16)y2;
            }
        } else {
            #pragma unroll
            for (int nt = 0; nt < 4; ++nt) {
                int ng = n0 + nt * 16 + c - 384;
                int vh = ng >> 5, d = ng & 31;
                vtws[((size_t)(b * NKVH + vh) * HDIM + d) * SEQ + s] = (bf16)acc[nt][r];
            }
        }
    }
}

// ---------------------------------------------------------------------------
// Kernel 2: causal flash attention, 32 q/wave, async global_load_lds staging,
// RING-3 LDS + COUNTED vmcnt + RAW s_barrier (T3/T4).
// Per step s: wait vmcnt(2) (retires chunk s, issued 2 steps ago -- fully
// hidden), raw barrier, issue DMA for chunk s+2, compute chunk s.  Chunk s+1
// loads stay IN FLIGHT across the barrier (no vmcnt(0) drain).  Ring safety
// (R=3): buffer re-issued at step s was last read at step s-1, separated by
// the step-s barrier.  Cross-half T pairing: co-resident blocks sum to 68
// steps per CU.  Shuffle-free S->P->PV; no-max softmax; l via ones-MFMA;
// h = wg&7 pins each KV stream to one XCD's L2.
// ---------------------------------------------------------------------------
__global__ __launch_bounds__(256, 2) void attn_fwd(
    const bf16* __restrict__ qws, const bf16* __restrict__ kws,
    const bf16* __restrict__ vtws, bf16* __restrict__ att)
{
    __shared__ bf16 Kb[3][64 * 32];     // [key][d] linear, 4KB per ring slot
    __shared__ bf16 Vb[3][32 * 64];     // [d][key], swizzled via global src
    __shared__ float tr[4][16 * 33];
    const int t = threadIdx.x;
    const int w = t >> 6, lane = t & 63;
    const int g = lane >> 4, c = lane & 15;
    const int wg = blockIdx.x;
    const int h = wg & 7;                    // XCD pin (consecutive wgs round-robin)
    const int rem = (wg >> 3) & 31;          // 0..31 within half
    const int b = rem & 1;
    const int tp = rem >> 1;                 // 0..15
    const int T = (wg < 256) ? (31 - tp) : tp;   // cross-half pairing: sums to 31
    const int kvh = h >> 1;
    const bf16* Kg = kws + (size_t)(b * NKVH + kvh) * SEQ * HDIM;
    const bf16* Vg = vtws + (size_t)(b * NKVH + kvh) * HDIM * SEQ;
    const int nsteps = 2 * T + 2;            // 64-key chunks covering [0,(T+1)*128)
    const int q0 = T * 128 + w * 32;         // wave's first query
    const int d_w = 2 * T + (w >> 1);        // wave's diagonal chunk

    const bf16* Qb = qws + (size_t)(b * NHEAD + h) * SEQ * HDIM;
    bf16x8 qf0 = *(const bf16x8*)&Qb[(size_t)(q0 + c) * HDIM + g * 8];
    bf16x8 qf1 = *(const bf16x8*)&Qb[(size_t)(q0 + 16 + c) * HDIM + g * 8];

    // async staging: per-lane global src, wave-uniform LDS dest (+lane*16 HW)
    const int sd = t >> 3, sseg = t & 7;
    const bf16* kg_t = Kg + t * 8;                                    // + ch*2048
    const bf16* vg_t = Vg + (size_t)sd * SEQ + (sseg ^ (sd & 7)) * 8; // + ch*64
    char* kls = (char*)&Kb[0][0] + w * 1024;   // + ring*4096
    char* vls = (char*)&Vb[0][0] + w * 1024;

    // fragment read offsets
    const int kperm = 8 * (c >> 2) + (c & 3);
    const int kro = kperm * 64 + g * 16;           // byte offset within ring slot
    const int cx = c & 7;
    const int vro0 = c * 128, vro1 = (16 + c) * 128;

    const f32x4 zf = {0.f, 0.f, 0.f, 0.f};
    union { uint32_t u[4]; bf16x8 v; } onesf;
    onesf.u[0] = onesf.u[1] = onesf.u[2] = onesf.u[3] = 0x3F803F80u;

    f32x4 o00 = zf, o01 = zf, ol0 = zf;      // subtile 0 (q0..q0+15)
    f32x4 o10 = zf, o11 = zf, ol1 = zf;      // subtile 1 (q0+16..q0+31)

    // prologue: stage chunks 0 and 1 into ring slots 0,1 (4 DMA ops in flight)
    gld_lds16(kg_t, kls);
    gld_lds16(vg_t, vls);
    gld_lds16(kg_t + 2048, kls + 4096);
    gld_lds16(vg_t + 64, vls + 4096);

    int rc = 0, ri = 2;                      // ring: compute slot / issue slot
    #pragma unroll 1
    for (int s = 0; s < nsteps; ++s) {
        // (1) retire chunk s only (chunk s+1 stays in flight across barrier)
        if (s + 1 < nsteps) asm volatile("s_waitcnt vmcnt(2)" ::: "memory");
        else                asm volatile("s_waitcnt vmcnt(0)" ::: "memory");
        __builtin_amdgcn_s_barrier();
        __builtin_amdgcn_sched_barrier(0);
        // (2) issue DMA for chunk s+2 into ring slot ri (safe: slot last read
        //     at step s-1, all waves passed this step's barrier since)
        const int sn = s + 2;
        if (sn < nsteps) {
            gld_lds16(kg_t + (size_t)sn * 2048, kls + ri * 4096);
            gld_lds16(vg_t + (size_t)sn * 64, vls + ri * 4096);
        }
        __builtin_amdgcn_sched_barrier(0);
        // (3) compute chunk s from ring slot rc
        if (s <= d_w) {
            const char* kbuf = (const char*)&Kb[0][0] + rc * 4096;
            const char* vbuf = (const char*)&Vb[0][0] + rc * 4096;

            bf16x8 kf0 = *(const bf16x8*)(kbuf + kro);
            bf16x8 kf1 = *(const bf16x8*)(kbuf + kro + 256);
            bf16x8 kf2 = *(const bf16x8*)(kbuf + kro + 2048);
            bf16x8 kf3 = *(const bf16x8*)(kbuf + kro + 2304);
            bf16x8 vf00 = *(const bf16x8*)(vbuf + vro0 + ((g ^ cx) << 4));
            bf16x8 vf01 = *(const bf16x8*)(vbuf + vro1 + ((g ^ cx) << 4));
            bf16x8 vf10 = *(const bf16x8*)(vbuf + vro0 + (((4 + g) ^ cx) << 4));
            bf16x8 vf11 = *(const bf16x8*)(vbuf + vro1 + (((4 + g) ^ cx) << 4));

            const bool diag = (s == d_w);
            const int qbase = (w & 1) * 32 + c;

            // ---- subtile 0 ----
            {
                f32x4 st0 = __builtin_amdgcn_mfma_f32_16x16x32_bf16(kf0, qf0, zf, 0, 0, 0);
                f32x4 st1 = __builtin_amdgcn_mfma_f32_16x16x32_bf16(kf1, qf0, zf, 0, 0, 0);
                f32x4 st2 = __builtin_amdgcn_mfma_f32_16x16x32_bf16(kf2, qf0, zf, 0, 0, 0);
                f32x4 st3 = __builtin_amdgcn_mfma_f32_16x16x32_bf16(kf3, qf0, zf, 0, 0, 0);
                if (diag) {
                    const int qoff = qbase;
                    #pragma unroll
                    for (int r = 0; r < 4; ++r) {
                        if (8 * g + r > qoff)          st0[r] = -1e30f;
                        if (8 * g + 4 + r > qoff)      st1[r] = -1e30f;
                        if (32 + 8 * g + r > qoff)     st2[r] = -1e30f;
                        if (32 + 8 * g + 4 + r > qoff) st3[r] = -1e30f;
                    }
                }
                float p00 = fexp2(st0[0]), p01 = fexp2(st0[1]), p02 = fexp2(st0[2]), p03 = fexp2(st0[3]);
                float p10 = fexp2(st1[0]), p11 = fexp2(st1[1]), p12 = fexp2(st1[2]), p13 = fexp2(st1[3]);
                float p20 = fexp2(st2[0]), p21 = fexp2(st2[1]), p22 = fexp2(st2[2]), p23 = fexp2(st2[3]);
                float p30 = fexp2(st3[0]), p31 = fexp2(st3[1]), p32 = fexp2(st3[2]), p33 = fexp2(st3[3]);
                union { uint32_t u[4]; bf16x8 v; } pb0, pb1;
                asm("v_cvt_pk_bf16_f32 %0, %1, %2" : "=v"(pb0.u[0]) : "v"(p00), "v"(p01));
                asm("v_cvt_pk_bf16_f32 %0, %1, %2" : "=v"(pb0.u[1]) : "v"(p02), "v"(p03));
                asm("v_cvt_pk_bf16_f32 %0, %1, %2" : "=v"(pb0.u[2]) : "v"(p10), "v"(p11));
                asm("v_cvt_pk_bf16_f32 %0, %1, %2" : "=v"(pb0.u[3]) : "v"(p12), "v"(p13));
                asm("v_cvt_pk_bf16_f32 %0, %1, %2" : "=v"(pb1.u[0]) : "v"(p20), "v"(p21));
                asm("v_cvt_pk_bf16_f32 %0, %1, %2" : "=v"(pb1.u[1]) : "v"(p22), "v"(p23));
                asm("v_cvt_pk_bf16_f32 %0, %1, %2" : "=v"(pb1.u[2]) : "v"(p30), "v"(p31));
                asm("v_cvt_pk_bf16_f32 %0, %1, %2" : "=v"(pb1.u[3]) : "v"(p32), "v"(p33));
                o00 = __builtin_amdgcn_mfma_f32_16x16x32_bf16(vf00, pb0.v, o00, 0, 0, 0);
                o01 = __builtin_amdgcn_mfma_f32_16x16x32_bf16(vf01, pb0.v, o01, 0, 0, 0);
                ol0 = __builtin_amdgcn_mfma_f32_16x16x32_bf16(onesf.v, pb0.v, ol0, 0, 0, 0);
                o00 = __builtin_amdgcn_mfma_f32_16x16x32_bf16(vf10, pb1.v, o00, 0, 0, 0);
                o01 = __builtin_amdgcn_mfma_f32_16x16x32_bf16(vf11, pb1.v, o01, 0, 0, 0);
                ol0 = __builtin_amdgcn_mfma_f32_16x16x32_bf16(onesf.v, pb1.v, ol0, 0, 0, 0);
            }
            // ---- subtile 1 ----
            {
                f32x4 st0 = __builtin_amdgcn_mfma_f32_16x16x32_bf16(kf0, qf1, zf, 0, 0, 0);
                f32x4 st1 = __builtin_amdgcn_mfma_f32_16x16x32_bf16(kf1, qf1, zf, 0, 0, 0);
                f32x4 st2 = __builtin_amdgcn_mfma_f32_16x16x32_bf16(kf2, qf1, zf, 0, 0, 0);
                f32x4 st3 = __builtin_amdgcn_mfma_f32_16x16x32_bf16(kf3, qf1, zf, 0, 0, 0);
                if (diag) {
                    const int qoff = qbase + 16;
                    #pragma unroll
                    for (int r = 0; r < 4; ++r) {
                        if (8 * g + r > qoff)          st0[r] = -1e30f;
                        if (8 * g + 4 + r > qoff)      st1[r] = -1e30f;
                        if (32 + 8 * g + r > qoff)     st2[r] = -1e30f;
                        if (32 + 8 * g + 4 + r > qoff) st3[r] = -1e30f;
                    }
                }
                float p00 = fexp2(st0[0]), p01 = fexp2(st0[1]), p02 = fexp2(st0[2]), p03 = fexp2(st0[3]);
                float p10 = fexp2(st1[0]), p11 = fexp2(st1[1]), p12 = fexp2(st1[2]), p13 = fexp2(st1[3]);
                float p20 = fexp2(st2[0]), p21 = fexp2(st2[1]), p22 = fexp2(st2[2]), p23 = fexp2(st2[3]);
                float p30 = fexp2(st3[0]), p31 = fexp2(st3[1]), p32 = fexp2(st3[2]), p33 = fexp2(st3[3]);
                union { uint32_t u[4]; bf16x8 v; } pb0, pb1;
                asm("v_cvt_pk_bf16_f32 %0, %1, %2" : "=v"(pb0.u[0]) : "v"(p00), "v"(p01));
                asm("v_cvt_pk_bf16_f32 %0, %1, %2" : "=v"(pb0.u[1]) : "v"(p02), "v"(p03));
                asm("v_cvt_pk_bf16_f32 %0, %1, %2" : "=v"(pb0.u[2]) : "v"(p10), "v"(p11));
                asm("v_cvt_pk_bf16_f32 %0, %1, %2" : "=v"(pb0.u[3]) : "v"(p12), "v"(p13));
                asm("v_cvt_pk_bf16_f32 %0, %1, %2" : "=v"(pb1.u[0]) : "v"(p20), "v"(p21));
                asm("v_cvt_pk_bf16_f32 %0, %1, %2" : "=v"(pb1.u[1]) : "v"(p22), "v"(p23));
                asm("v_cvt_pk_bf16_f32 %0, %1, %2" : "=v"(pb1.u[2]) : "v"(p30), "v"(p31));
                asm("v_cvt_pk_bf16_f32 %0, %1, %2" : "=v"(pb1.u[3]) : "v"(p32), "v"(p33));
                o10 = __builtin_amdgcn_mfma_f32_16x16x32_bf16(vf00, pb0.v, o10, 0, 0, 0);
                o11 = __builtin_amdgcn_mfma_f32_16x16x32_bf16(vf01, pb0.v, o11, 0, 0, 0);
                ol1 = __builtin_amdgcn_mfma_f32_16x16x32_bf16(onesf.v, pb0.v, ol1, 0, 0, 0);
                o10 = __builtin_amdgcn_mfma_f32_16x16x32_bf16(vf10, pb1.v, o10, 0, 0, 0);
                o11 = __builtin_amdgcn_mfma_f32_16x16x32_bf16(vf11, pb1.v, o11, 0, 0, 0);
                ol1 = __builtin_amdgcn_mfma_f32_16x16x32_bf16(onesf.v, pb1.v, ol1, 0, 0, 0);
            }
        }
        rc = (rc == 2) ? 0 : rc + 1;
        ri = (ri == 2) ? 0 : ri + 1;
    }

    // epilogue: both subtiles (per-wave private tr slice, sequential -> safe)
    #pragma unroll 1
    for (int j = 0; j < 2; ++j) {
        f32x4 a0 = j ? o10 : o00;
        f32x4 a1 = j ? o11 : o01;
        f32x4 al = j ? ol1 : ol0;
        float inv = 1.0f / al[0];
        #pragma unroll
        for (int r = 0; r < 4; ++r) {
            tr[w][c * 33 + 4 * g + r]      = a0[r] * inv;
            tr[w][c * 33 + 16 + 4 * g + r] = a1[r] * inv;
        }
        int q = lane >> 2, dp = (lane & 3) * 8;
        uint32_t u0 = pack_bf16(tr[w][q * 33 + dp + 0], tr[w][q * 33 + dp + 1]);
        uint32_t u1 = pack_bf16(tr[w][q * 33 + dp + 2], tr[w][q * 33 + dp + 3]);
        uint32_t u2 = pack_bf16(tr[w][q * 33 + dp + 4], tr[w][q * 33 + dp + 5]);
        uint32_t u3 = pack_bf16(tr[w][q * 33 + dp + 6], tr[w][q * 33 + dp + 7]);
        size_t base = ((size_t)b * SEQ + q0 + j * 16 + q) * HID + h * HDIM + dp;
        *(uint4*)&att[base] = make_uint4(u0, u1, u2, u3);
    }
}

// ---------------------------------------------------------------------------
// Kernel 3: output projection (unchanged).
// ---------------------------------------------------------------------------
__global__ __launch_bounds__(256) void out_proj(
    const bf16* __restrict__ att, const float* __restrict__ Wo,
    float* __restrict__ out)
{
    __shared__ bf16 As[64][136];
    __shared__ bf16 Bs[64][136];
    const int t = threadIdx.x;
    const int wid = t >> 6, lane = t & 63;
    const int g = lane >> 4, c = lane & 15;
    const int n0 = blockIdx.x * 64;
    const int m0 = blockIdx.y * 64;

    const f32x4 zf = {0.f, 0.f, 0.f, 0.f};
    f32x4 acc[4] = {zf, zf, zf, zf};

    const int c4 = t & 31;
    const int rb = t >> 5;

    for (int ks = 0; ks < 256; ks += 128) {
        __syncthreads();
        #pragma unroll
        for (int i = 0; i < 8; ++i) {
            int row = i * 8 + rb;
            ushort4 v = *(const ushort4*)&att[(size_t)(m0 + row) * HID + ks + c4 * 4];
            *(ushort4*)&As[row][c4 * 4] = v;
        }
        #pragma unroll
        for (int i = 0; i < 8; ++i) {
            int row = i * 8 + rb;
            float4 v = *(const float4*)&Wo[(size_t)(n0 + row) * HID + ks + c4 * 4];
            ushort4 w; w.x = bfbits(v.x); w.y = bfbits(v.y); w.z = bfbits(v.z); w.w = bfbits(v.w);
            *(ushort4*)&Bs[row][c4 * 4] = w;
        }
        __syncthreads();
        #pragma unroll
        for (int kk = 0; kk < 128; kk += 32) {
            bf16x8 af = *(const bf16x8*)&As[wid * 16 + c][kk + g * 8];
            #pragma unroll
            for (int nt = 0; nt < 4; ++nt) {
                bf16x8 bfr = *(const bf16x8*)&Bs[nt * 16 + c][kk + g * 8];
                acc[nt] = __builtin_amdgcn_mfma_f32_16x16x32_bf16(af, bfr, acc[nt], 0, 0, 0);
            }
        }
    }

    #pragma unroll
    for (int nt = 0; nt < 4; ++nt) {
        #pragma unroll
        for (int r = 0; r < 4; ++r) {
            int m = m0 + wid * 16 + g * 4 + r;
            out[(size_t)m * HID + n0 + nt * 16 + c] = acc[nt][r];
        }
    }
}

extern "C" void kernel_launch(void* const* d_in, const int* in_sizes, int n_in,
                              void* d_out, int out_size, void* d_ws, size_t ws_size,
                              hipStream_t stream) {
    const float* hs = (const float*)d_in[0];
    const float* Wq = (const float*)d_in[1];
    const float* Wk = (const float*)d_in[2];
    const float* Wv = (const float*)d_in[3];
    const float* Wo = (const float*)d_in[4];
    char* ws = (char*)d_ws;
    bf16* qws  = (bf16*)(ws);                 // [2][8][4096][32]  4,194,304 B
    bf16* kws  = (bf16*)(ws + 4194304);       // [2][4][4096][32]  2,097,152 B
    bf16* vtws = (bf16*)(ws + 6291456);       // [2][4][32][4096]  2,097,152 B
    bf16* att  = (bf16*)(ws + 8388608);       // [2][4096][256]    4,194,304 B

    qkv_proj<<<dim3(8, 128), 256, 0, stream>>>(hs, Wq, Wk, Wv, qws, kws, vtws);
    attn_fwd<<<512, 256, 0, stream>>>(qws, kws, vtws, att);
    out_proj<<<dim3(4, 128), 256, 0, stream>>>(att, Wo, (float*)d_out);
}

// Round 11
// 72.956 us; speedup vs baseline: 1.1465x; 1.1465x over previous
//
#include <hip/hip_runtime.h>
#include <hip/hip_bf16.h>
#include <stdint.h>

#define NB 2
#define SEQ 4096
#define HID 256
#define NHEAD 8
#define NKVH 4
#define HDIM 32

typedef __bf16 bf16;
typedef __bf16 bf16x8 __attribute__((ext_vector_type(8)));
typedef float f32x4 __attribute__((ext_vector_type(4)));

static __device__ __forceinline__ uint16_t bfbits(float f) {
    bf16 h = (bf16)f;
    return __builtin_bit_cast(uint16_t, h);
}
static __device__ __forceinline__ uint32_t pack_bf16(float lo, float hi) {
    return (uint32_t)bfbits(lo) | ((uint32_t)bfbits(hi) << 16);
}
// raw v_exp_f32: no libm range wrapper.  exp2(-1e30) == +0 in HW.
static __device__ __forceinline__ float fexp2(float x) {
#if __has_builtin(__builtin_amdgcn_exp2f)
    return __builtin_amdgcn_exp2f(x);
#else
    float r; asm("v_exp_f32 %0, %1" : "=v"(r) : "v"(x)); return r;
#endif
}
// async global->LDS DMA, 16B per lane.  LDS dest = wave-uniform base +
// lane*16 (hardware rule); global src is per-lane.
static __device__ __forceinline__ void gld_lds16(const void* g, void* l) {
    __builtin_amdgcn_global_load_lds(
        (const __attribute__((address_space(1))) void*)g,
        (__attribute__((address_space(3))) void*)l, 16, 0, 0);
}

// ---------------------------------------------------------------------------
// Kernel 1: QKV projection + RoPE (unchanged).
// ---------------------------------------------------------------------------
__global__ __launch_bounds__(256) void qkv_proj(
    const float* __restrict__ hs, const float* __restrict__ Wq,
    const float* __restrict__ Wk, const float* __restrict__ Wv,
    bf16* __restrict__ qws, bf16* __restrict__ kws, bf16* __restrict__ vtws)
{
    __shared__ bf16 As[64][136];
    __shared__ bf16 Bs[64][136];
    const int t = threadIdx.x;
    const int wid = t >> 6, lane = t & 63;
    const int g = lane >> 4, c = lane & 15;
    const int n0 = blockIdx.x * 64;
    const int m0 = blockIdx.y * 64;

    const float* bsrc; int ro;
    if (n0 < 256)      { bsrc = Wq; ro = n0; }
    else if (n0 < 384) { bsrc = Wk; ro = n0 - 256; }
    else               { bsrc = Wv; ro = n0 - 384; }

    const f32x4 zf = {0.f, 0.f, 0.f, 0.f};
    f32x4 acc[4] = {zf, zf, zf, zf};

    const int c4 = t & 31;
    const int rb = t >> 5;

    for (int ks = 0; ks < 256; ks += 128) {
        __syncthreads();
        #pragma unroll
        for (int i = 0; i < 8; ++i) {
            int row = i * 8 + rb;
            float4 v = *(const float4*)&hs[(size_t)(m0 + row) * HID + ks + c4 * 4];
            ushort4 w; w.x = bfbits(v.x); w.y = bfbits(v.y); w.z = bfbits(v.z); w.w = bfbits(v.w);
            *(ushort4*)&As[row][c4 * 4] = w;
        }
        #pragma unroll
        for (int i = 0; i < 8; ++i) {
            int row = i * 8 + rb;
            float4 v = *(const float4*)&bsrc[(size_t)(ro + row) * HID + ks + c4 * 4];
            ushort4 w; w.x = bfbits(v.x); w.y = bfbits(v.y); w.z = bfbits(v.z); w.w = bfbits(v.w);
            *(ushort4*)&Bs[row][c4 * 4] = w;
        }
        __syncthreads();
        #pragma unroll
        for (int kk = 0; kk < 128; kk += 32) {
            bf16x8 af = *(const bf16x8*)&As[wid * 16 + c][kk + g * 8];
            #pragma unroll
            for (int nt = 0; nt < 4; ++nt) {
                bf16x8 bfr = *(const bf16x8*)&Bs[nt * 16 + c][kk + g * 8];
                acc[nt] = __builtin_amdgcn_mfma_f32_16x16x32_bf16(af, bfr, acc[nt], 0, 0, 0);
            }
        }
    }

    const float qscale = 1.4426950408889634f * 0.17677669529663687f; // log2e/sqrt(32)
    const float invf = exp2f(-0.83048202372184f * (float)c);          // 10000^(-c/16)
    #pragma unroll
    for (int r = 0; r < 4; ++r) {
        int m = m0 + wid * 16 + g * 4 + r;
        int b = m >> 12, s = m & (SEQ - 1);
        float sn, cs;
        sincosf((float)s * invf, &sn, &cs);
        if (n0 < 256) {
            #pragma unroll
            for (int np = 0; np < 4; np += 2) {
                int h = (n0 + np * 16) >> 5;
                float x1 = acc[np][r], x2 = acc[np + 1][r];
                float y1 = (x1 * cs - x2 * sn) * qscale;
                float y2 = (x2 * cs + x1 * sn) * qscale;
                size_t base = ((size_t)(b * NHEAD + h) * SEQ + s) * HDIM;
                qws[base + c] = (bf16)y1;
                qws[base + 16 + c] = (bf16)y2;
            }
        } else if (n0 < 384) {
            #pragma unroll
            for (int np = 0; np < 4; np += 2) {
                int kh = (n0 - 256 + np * 16) >> 5;
                float x1 = acc[np][r], x2 = acc[np + 1][r];
                float y1 = x1 * cs - x2 * sn;
                float y2 = x2 * cs + x1 * sn;
                size_t base = ((size_t)(b * NKVH + kh) * SEQ + s) * HDIM;
                kws[base + c] = (bf16)y1;
                kws[base + 16 + c] = (bf16)y2;
            }
        } else {
            #pragma unroll
            for (int nt = 0; nt < 4; ++nt) {
                int ng = n0 + nt * 16 + c - 384;
                int vh = ng >> 5, d = ng & 31;
                vtws[((size_t)(b * NKVH + vh) * HDIM + d) * SEQ + s] = (bf16)acc[nt][r];
            }
        }
    }
}

// ---------------------------------------------------------------------------
// Kernel 2: causal flash attention, 32 q/wave, async global_load_lds staging,
// 128-KEY CHUNKS (R8 structure, doubled chunk).  DMA for chunk s+1 issued at
// step top; __syncthreads at step end drains it -- compute (~1200cyc) now
// covers the ~900cyc DMA latency, and barrier count halves (33/CU vs 68).
// With 128-q tiles + 128-k chunks every wave is active every step; diagonal
// is the LAST step only (wave-uniform j>w skip inside it).  Shuffle-free
// S->P->PV via permuted K rows; no-max softmax; l via ones-MFMA; h = wg&7
// pins each KV stream to one XCD's L2; long/short tiles pair across halves.
// ---------------------------------------------------------------------------
__global__ __launch_bounds__(256, 2) void attn_fwd(
    const bf16* __restrict__ qws, const bf16* __restrict__ kws,
    const bf16* __restrict__ vtws, bf16* __restrict__ att)
{
    __shared__ bf16 Kb[2][128 * 32];    // [key][d] linear, 8KB per buffer
    __shared__ bf16 Vb[2][32 * 128];    // [d][key] 256B rows, swizzled via src
    __shared__ float tr[4][16 * 33];
    const int t = threadIdx.x;
    const int w = t >> 6, lane = t & 63;
    const int g = lane >> 4, c = lane & 15;
    const int wg = blockIdx.x;
    const int h = wg & 7;                    // XCD pin
    const int rem = (wg >> 3) & 31;
    const int b = rem & 1;
    const int tp = rem >> 1;                 // 0..15
    const int T = (wg < 256) ? (31 - tp) : tp;   // halves pair long+short
    const int kvh = h >> 1;
    const bf16* Kg = kws + (size_t)(b * NKVH + kvh) * SEQ * HDIM;
    const bf16* Vg = vtws + (size_t)(b * NKVH + kvh) * HDIM * SEQ;
    const int nsteps = T + 1;                // 128-key chunks
    const int q0 = T * 128 + w * 32;         // wave's first query

    const bf16* Qb = qws + (size_t)(b * NHEAD + h) * SEQ * HDIM;
    bf16x8 qf0 = *(const bf16x8*)&Qb[(size_t)(q0 + c) * HDIM + g * 8];
    bf16x8 qf1 = *(const bf16x8*)&Qb[(size_t)(q0 + 16 + c) * HDIM + g * 8];

    // staging: 4 gld_lds per thread per chunk (2 K + 2 V), 16B each.
    // K: linear [key][d]; thread t covers bytes t*16 (callA) / 4096+t*16 (B).
    const bf16* kg_t = Kg + t * 8;                    // + ch*4096 elems
    // V: [d][key] 256B rows; LDS byte t*16 -> d=t>>4, seg_l=t&15; source seg
    // swizzled: seg_s = (t&8) | ((t&7) ^ ((t>>4)&7)).  Rows 16..31 same seg.
    const int seg_s = (t & 8) | ((t & 7) ^ ((t >> 4) & 7));
    const bf16* vg_tA = Vg + (size_t)(t >> 4) * SEQ + seg_s * 8;        // + ch*128
    const bf16* vg_tB = vg_tA + (size_t)16 * SEQ;
    char* kl = (char*)&Kb[0][0] + w * 1024;           // + buf*8192 (+4096 callB)
    char* vl = (char*)&Vb[0][0] + w * 1024;

    // fragment read offsets
    const int kperm = 8 * (c >> 2) + (c & 3);
    const int kro = kperm * 64 + g * 16;              // within j-subchunk (2KB)
    const int cx = c & 7;
    const int vrow0 = c * 256;                        // row c; +4096 for row 16+c
    // voff[j] = ((j&2)<<6) + ((((j&1)*4 + g) ^ cx) << 4)
    const int voff0 = ((g) ^ cx) << 4;
    const int voff1 = ((4 + g) ^ cx) << 4;
    const int voff2 = 128 + voff0;
    const int voff3 = 128 + voff1;

    const f32x4 zf = {0.f, 0.f, 0.f, 0.f};
    union { uint32_t u[4]; bf16x8 v; } onesf;
    onesf.u[0] = onesf.u[1] = onesf.u[2] = onesf.u[3] = 0x3F803F80u;

    f32x4 o00 = zf, o01 = zf, ol0 = zf;      // subtile 0 (q0..q0+15)
    f32x4 o10 = zf, o11 = zf, ol1 = zf;      // subtile 1 (q0+16..q0+31)

    // prologue: stage chunk 0
    gld_lds16(kg_t, kl);
    gld_lds16(kg_t + 2048, kl + 4096);
    gld_lds16(vg_tA, vl);
    gld_lds16(vg_tB, vl + 4096);
    __syncthreads();

    #pragma unroll 1
    for (int s = 0; s < nsteps; ++s) {
        // (1) issue async DMA for chunk s+1 into the other buffer
        const int sn = s + 1;
        if (sn < nsteps) {
            const int bo = (sn & 1) * 8192;
            gld_lds16(kg_t + (size_t)sn * 4096, kl + bo);
            gld_lds16(kg_t + (size_t)sn * 4096 + 2048, kl + bo + 4096);
            gld_lds16(vg_tA + (size_t)sn * 128, vl + bo);
            gld_lds16(vg_tB + (size_t)sn * 128, vl + bo + 4096);
        }
        // (2) compute chunk s from buf[s&1]
        const char* kbuf = (const char*)&Kb[s & 1][0];
        const char* vbuf = (const char*)&Vb[s & 1][0];
        const bool diag = (s == T);
        const int qo0 = w * 32 + c;          // query offset within chunk, subtile 0
        #pragma unroll
        for (int j = 0; j < 4; ++j) {
            if (diag && j > w) continue;      // fully-masked j-group (wave-uniform)
            const int voffj = (j == 0) ? voff0 : (j == 1) ? voff1 : (j == 2) ? voff2 : voff3;
            bf16x8 kf0 = *(const bf16x8*)(kbuf + j * 2048 + kro);
            bf16x8 kf1 = *(const bf16x8*)(kbuf + j * 2048 + kro + 256);
            bf16x8 vfA = *(const bf16x8*)(vbuf + vrow0 + voffj);
            bf16x8 vfB = *(const bf16x8*)(vbuf + 4096 + vrow0 + voffj);
            // ---- subtile 0 ----
            {
                f32x4 st0 = __builtin_amdgcn_mfma_f32_16x16x32_bf16(kf0, qf0, zf, 0, 0, 0);
                f32x4 st1 = __builtin_amdgcn_mfma_f32_16x16x32_bf16(kf1, qf0, zf, 0, 0, 0);
                if (diag) {
                    #pragma unroll
                    for (int r = 0; r < 4; ++r) {
                        if (j * 32 + 8 * g + r > qo0)     st0[r] = -1e30f;
                        if (j * 32 + 8 * g + 4 + r > qo0) st1[r] = -1e30f;
                    }
                }
                float p0 = fexp2(st0[0]), p1 = fexp2(st0[1]), p2 = fexp2(st0[2]), p3 = fexp2(st0[3]);
                float p4 = fexp2(st1[0]), p5 = fexp2(st1[1]), p6 = fexp2(st1[2]), p7 = fexp2(st1[3]);
                union { uint32_t u[4]; bf16x8 v; } pb;
                asm("v_cvt_pk_bf16_f32 %0, %1, %2" : "=v"(pb.u[0]) : "v"(p0), "v"(p1));
                asm("v_cvt_pk_bf16_f32 %0, %1, %2" : "=v"(pb.u[1]) : "v"(p2), "v"(p3));
                asm("v_cvt_pk_bf16_f32 %0, %1, %2" : "=v"(pb.u[2]) : "v"(p4), "v"(p5));
                asm("v_cvt_pk_bf16_f32 %0, %1, %2" : "=v"(pb.u[3]) : "v"(p6), "v"(p7));
                o00 = __builtin_amdgcn_mfma_f32_16x16x32_bf16(vfA, pb.v, o00, 0, 0, 0);
                o01 = __builtin_amdgcn_mfma_f32_16x16x32_bf16(vfB, pb.v, o01, 0, 0, 0);
                ol0 = __builtin_amdgcn_mfma_f32_16x16x32_bf16(onesf.v, pb.v, ol0, 0, 0, 0);
            }
            // ---- subtile 1 ----
            {
                f32x4 st0 = __builtin_amdgcn_mfma_f32_16x16x32_bf16(kf0, qf1, zf, 0, 0, 0);
                f32x4 st1 = __builtin_amdgcn_mfma_f32_16x16x32_bf16(kf1, qf1, zf, 0, 0, 0);
                if (diag) {
                    const int qo1 = qo0 + 16;
                    #pragma unroll
                    for (int r = 0; r < 4; ++r) {
                        if (j * 32 + 8 * g + r > qo1)     st0[r] = -1e30f;
                        if (j * 32 + 8 * g + 4 + r > qo1) st1[r] = -1e30f;
                    }
                }
                float p0 = fexp2(st0[0]), p1 = fexp2(st0[1]), p2 = fexp2(st0[2]), p3 = fexp2(st0[3]);
                float p4 = fexp2(st1[0]), p5 = fexp2(st1[1]), p6 = fexp2(st1[2]), p7 = fexp2(st1[3]);
                union { uint32_t u[4]; bf16x8 v; } pb;
                asm("v_cvt_pk_bf16_f32 %0, %1, %2" : "=v"(pb.u[0]) : "v"(p0), "v"(p1));
                asm("v_cvt_pk_bf16_f32 %0, %1, %2" : "=v"(pb.u[1]) : "v"(p2), "v"(p3));
                asm("v_cvt_pk_bf16_f32 %0, %1, %2" : "=v"(pb.u[2]) : "v"(p4), "v"(p5));
                asm("v_cvt_pk_bf16_f32 %0, %1, %2" : "=v"(pb.u[3]) : "v"(p6), "v"(p7));
                o10 = __builtin_amdgcn_mfma_f32_16x16x32_bf16(vfA, pb.v, o10, 0, 0, 0);
                o11 = __builtin_amdgcn_mfma_f32_16x16x32_bf16(vfB, pb.v, o11, 0, 0, 0);
                ol1 = __builtin_amdgcn_mfma_f32_16x16x32_bf16(onesf.v, pb.v, ol1, 0, 0, 0);
            }
        }
        // (3) barrier: drains DMA (vmcnt 0) + orders LDS buffer reuse
        __syncthreads();
    }

    // epilogue: both subtiles (per-wave private tr slice, sequential -> safe)
    #pragma unroll 1
    for (int j = 0; j < 2; ++j) {
        f32x4 a0 = j ? o10 : o00;
        f32x4 a1 = j ? o11 : o01;
        f32x4 al = j ? ol1 : ol0;
        float inv = 1.0f / al[0];
        #pragma unroll
        for (int r = 0; r < 4; ++r) {
            tr[w][c * 33 + 4 * g + r]      = a0[r] * inv;
            tr[w][c * 33 + 16 + 4 * g + r] = a1[r] * inv;
        }
        int q = lane >> 2, dp = (lane & 3) * 8;
        uint32_t u0 = pack_bf16(tr[w][q * 33 + dp + 0], tr[w][q * 33 + dp + 1]);
        uint32_t u1 = pack_bf16(tr[w][q * 33 + dp + 2], tr[w][q * 33 + dp + 3]);
        uint32_t u2 = pack_bf16(tr[w][q * 33 + dp + 4], tr[w][q * 33 + dp + 5]);
        uint32_t u3 = pack_bf16(tr[w][q * 33 + dp + 6], tr[w][q * 33 + dp + 7]);
        size_t base = ((size_t)b * SEQ + q0 + j * 16 + q) * HID + h * HDIM + dp;
        *(uint4*)&att[base] = make_uint4(u0, u1, u2, u3);
    }
}

// ---------------------------------------------------------------------------
// Kernel 3: output projection (unchanged).
// ---------------------------------------------------------------------------
__global__ __launch_bounds__(256) void out_proj(
    const bf16* __restrict__ att, const float* __restrict__ Wo,
    float* __restrict__ out)
{
    __shared__ bf16 As[64][136];
    __shared__ bf16 Bs[64][136];
    const int t = threadIdx.x;
    const int wid = t >> 6, lane = t & 63;
    const int g = lane >> 4, c = lane & 15;
    const int n0 = blockIdx.x * 64;
    const int m0 = blockIdx.y * 64;

    const f32x4 zf = {0.f, 0.f, 0.f, 0.f};
    f32x4 acc[4] = {zf, zf, zf, zf};

    const int c4 = t & 31;
    const int rb = t >> 5;

    for (int ks = 0; ks < 256; ks += 128) {
        __syncthreads();
        #pragma unroll
        for (int i = 0; i < 8; ++i) {
            int row = i * 8 + rb;
            ushort4 v = *(const ushort4*)&att[(size_t)(m0 + row) * HID + ks + c4 * 4];
            *(ushort4*)&As[row][c4 * 4] = v;
        }
        #pragma unroll
        for (int i = 0; i < 8; ++i) {
            int row = i * 8 + rb;
            float4 v = *(const float4*)&Wo[(size_t)(n0 + row) * HID + ks + c4 * 4];
            ushort4 w; w.x = bfbits(v.x); w.y = bfbits(v.y); w.z = bfbits(v.z); w.w = bfbits(v.w);
            *(ushort4*)&Bs[row][c4 * 4] = w;
        }
        __syncthreads();
        #pragma unroll
        for (int kk = 0; kk < 128; kk += 32) {
            bf16x8 af = *(const bf16x8*)&As[wid * 16 + c][kk + g * 8];
            #pragma unroll
            for (int nt = 0; nt < 4; ++nt) {
                bf16x8 bfr = *(const bf16x8*)&Bs[nt * 16 + c][kk + g * 8];
                acc[nt] = __builtin_amdgcn_mfma_f32_16x16x32_bf16(af, bfr, acc[nt], 0, 0, 0);
            }
        }
    }

    #pragma unroll
    for (int nt = 0; nt < 4; ++nt) {
        #pragma unroll
        for (int r = 0; r < 4; ++r) {
            int m = m0 + wid * 16 + g * 4 + r;
            out[(size_t)m * HID + n0 + nt * 16 + c] = acc[nt][r];
        }
    }
}

extern "C" void kernel_launch(void* const* d_in, const int* in_sizes, int n_in,
                              void* d_out, int out_size, void* d_ws, size_t ws_size,
                              hipStream_t stream) {
    const float* hs = (const float*)d_in[0];
    const float* Wq = (const float*)d_in[1];
    const float* Wk = (const float*)d_in[2];
    const float* Wv = (const float*)d_in[3];
    const float* Wo = (const float*)d_in[4];
    char* ws = (char*)d_ws;
    bf16* qws  = (bf16*)(ws);                 // [2][8][4096][32]  4,194,304 B
    bf16* kws  = (bf16*)(ws + 4194304);       // [2][4][4096][32]  2,097,152 B
    bf16* vtws = (bf16*)(ws + 6291456);       // [2][4][32][4096]  2,097,152 B
    bf16* att  = (bf16*)(ws + 8388608);       // [2][4096][256]    4,194,304 B

    qkv_proj<<<dim3(8, 128), 256, 0, stream>>>(hs, Wq, Wk, Wv, qws, kws, vtws);
    attn_fwd<<<512, 256, 0, stream>>>(qws, kws, vtws, att);
    out_proj<<<dim3(4, 128), 256, 0, stream>>>(att, Wo, (float*)d_out);
}

// Round 12
// 72.434 us; speedup vs baseline: 1.1548x; 1.0072x over previous
//
#include <hip/hip_runtime.h>
#include <hip/hip_bf16.h>
#include <stdint.h>

#define NB 2
#define SEQ 4096
#define HID 256
#define NHEAD 8
#define NKVH 4
#define HDIM 32

typedef __bf16 bf16;
typedef __bf16 bf16x8 __attribute__((ext_vector_type(8)));
typedef float f32x4 __attribute__((ext_vector_type(4)));

static __device__ __forceinline__ uint16_t bfbits(float f) {
    bf16 h = (bf16)f;
    return __builtin_bit_cast(uint16_t, h);
}
static __device__ __forceinline__ uint32_t pack_bf16(float lo, float hi) {
    return (uint32_t)bfbits(lo) | ((uint32_t)bfbits(hi) << 16);
}
// raw v_exp_f32: no libm range wrapper.  exp2(-1e30) == +0 in HW.
static __device__ __forceinline__ float fexp2(float x) {
#if __has_builtin(__builtin_amdgcn_exp2f)
    return __builtin_amdgcn_exp2f(x);
#else
    float r; asm("v_exp_f32 %0, %1" : "=v"(r) : "v"(x)); return r;
#endif
}
// async global->LDS DMA, 16B per lane.  LDS dest = wave-uniform base +
// lane*16 (hardware rule); global src is per-lane.
static __device__ __forceinline__ void gld_lds16(const void* g, void* l) {
    __builtin_amdgcn_global_load_lds(
        (const __attribute__((address_space(1))) void*)g,
        (__attribute__((address_space(3))) void*)l, 16, 0, 0);
}

// ---------------------------------------------------------------------------
// Kernel 1: QKV projection + RoPE (unchanged).
// ---------------------------------------------------------------------------
__global__ __launch_bounds__(256) void qkv_proj(
    const float* __restrict__ hs, const float* __restrict__ Wq,
    const float* __restrict__ Wk, const float* __restrict__ Wv,
    bf16* __restrict__ qws, bf16* __restrict__ kws, bf16* __restrict__ vtws)
{
    __shared__ bf16 As[64][136];
    __shared__ bf16 Bs[64][136];
    const int t = threadIdx.x;
    const int wid = t >> 6, lane = t & 63;
    const int g = lane >> 4, c = lane & 15;
    const int n0 = blockIdx.x * 64;
    const int m0 = blockIdx.y * 64;

    const float* bsrc; int ro;
    if (n0 < 256)      { bsrc = Wq; ro = n0; }
    else if (n0 < 384) { bsrc = Wk; ro = n0 - 256; }
    else               { bsrc = Wv; ro = n0 - 384; }

    const f32x4 zf = {0.f, 0.f, 0.f, 0.f};
    f32x4 acc[4] = {zf, zf, zf, zf};

    const int c4 = t & 31;
    const int rb = t >> 5;

    for (int ks = 0; ks < 256; ks += 128) {
        __syncthreads();
        #pragma unroll
        for (int i = 0; i < 8; ++i) {
            int row = i * 8 + rb;
            float4 v = *(const float4*)&hs[(size_t)(m0 + row) * HID + ks + c4 * 4];
            ushort4 w; w.x = bfbits(v.x); w.y = bfbits(v.y); w.z = bfbits(v.z); w.w = bfbits(v.w);
            *(ushort4*)&As[row][c4 * 4] = w;
        }
        #pragma unroll
        for (int i = 0; i < 8; ++i) {
            int row = i * 8 + rb;
            float4 v = *(const float4*)&bsrc[(size_t)(ro + row) * HID + ks + c4 * 4];
            ushort4 w; w.x = bfbits(v.x); w.y = bfbits(v.y); w.z = bfbits(v.z); w.w = bfbits(v.w);
            *(ushort4*)&Bs[row][c4 * 4] = w;
        }
        __syncthreads();
        #pragma unroll
        for (int kk = 0; kk < 128; kk += 32) {
            bf16x8 af = *(const bf16x8*)&As[wid * 16 + c][kk + g * 8];
            #pragma unroll
            for (int nt = 0; nt < 4; ++nt) {
                bf16x8 bfr = *(const bf16x8*)&Bs[nt * 16 + c][kk + g * 8];
                acc[nt] = __builtin_amdgcn_mfma_f32_16x16x32_bf16(af, bfr, acc[nt], 0, 0, 0);
            }
        }
    }

    const float qscale = 1.4426950408889634f * 0.17677669529663687f; // log2e/sqrt(32)
    const float invf = exp2f(-0.83048202372184f * (float)c);          // 10000^(-c/16)
    #pragma unroll
    for (int r = 0; r < 4; ++r) {
        int m = m0 + wid * 16 + g * 4 + r;
        int b = m >> 12, s = m & (SEQ - 1);
        float sn, cs;
        sincosf((float)s * invf, &sn, &cs);
        if (n0 < 256) {
            #pragma unroll
            for (int np = 0; np < 4; np += 2) {
                int h = (n0 + np * 16) >> 5;
                float x1 = acc[np][r], x2 = acc[np + 1][r];
                float y1 = (x1 * cs - x2 * sn) * qscale;
                float y2 = (x2 * cs + x1 * sn) * qscale;
                size_t base = ((size_t)(b * NHEAD + h) * SEQ + s) * HDIM;
                qws[base + c] = (bf16)y1;
                qws[base + 16 + c] = (bf16)y2;
            }
        } else if (n0 < 384) {
            #pragma unroll
            for (int np = 0; np < 4; np += 2) {
                int kh = (n0 - 256 + np * 16) >> 5;
                float x1 = acc[np][r], x2 = acc[np + 1][r];
                float y1 = x1 * cs - x2 * sn;
                float y2 = x2 * cs + x1 * sn;
                size_t base = ((size_t)(b * NKVH + kh) * SEQ + s) * HDIM;
                kws[base + c] = (bf16)y1;
                kws[base + 16 + c] = (bf16)y2;
            }
        } else {
            #pragma unroll
            for (int nt = 0; nt < 4; ++nt) {
                int ng = n0 + nt * 16 + c - 384;
                int vh = ng >> 5, d = ng & 31;
                vtws[((size_t)(b * NKVH + vh) * HDIM + d) * SEQ + s] = (bf16)acc[nt][r];
            }
        }
    }
}

// ---------------------------------------------------------------------------
// Kernel 2: causal flash attention, 16 q/wave, async global_load_lds staging,
// 64-key chunks (exact R8 pipeline), 4 BLOCKS/CU for 4 waves/SIMD TLP.
// R11 showed the kernel is latency-chained at ~1 wave/SIMD (Occupancy 11%):
// grid was only 2 blocks/CU.  This version: 64-query tiles -> 1024 blocks,
// LDS 24.4KB, __launch_bounds__(256,4) -> 4 co-resident blocks per CU.
// Dependent-chain latency now hidden by thread-level parallelism; the
// per-step DMA drain overlaps other blocks' compute.  Diagonal = last step;
// waves 0-1 skip the fully-masked upper 32 keys there (wave-uniform).
// Shuffle-free S->P->PV via permuted K rows; no-max softmax; l via
// ones-MFMA; h = wg&7 pins each KV stream to one XCD's L2; descending-T.
// ---------------------------------------------------------------------------
__global__ __launch_bounds__(256, 4) void attn_fwd(
    const bf16* __restrict__ qws, const bf16* __restrict__ kws,
    const bf16* __restrict__ vtws, bf16* __restrict__ att)
{
    __shared__ bf16 Kb[2][64 * 32];     // [key][d] linear, 4KB per buffer
    __shared__ bf16 Vb[2][32 * 64];     // [d][key], swizzled via global src
    __shared__ float tr[4][16 * 33];
    const int t = threadIdx.x;
    const int w = t >> 6, lane = t & 63;
    const int g = lane >> 4, c = lane & 15;
    const int wg = blockIdx.x;
    const int h = wg & 7;                    // XCD pin
    const int rest = wg >> 3;                // 0..127
    const int b = rest & 1;
    const int TT = 63 - (rest >> 1);         // descending workload: longest first
    const int kvh = h >> 1;
    const bf16* Kg = kws + (size_t)(b * NKVH + kvh) * SEQ * HDIM;
    const bf16* Vg = vtws + (size_t)(b * NKVH + kvh) * HDIM * SEQ;
    const int nsteps = TT + 1;               // 64-key chunks
    const int q0 = TT * 64 + w * 16;         // wave's 16 queries

    const bf16* Qb = qws + (size_t)(b * NHEAD + h) * SEQ * HDIM;
    bf16x8 qf = *(const bf16x8*)&Qb[(size_t)(q0 + c) * HDIM + g * 8];

    // async staging: per-lane global src, wave-uniform LDS dest (+lane*16 HW)
    const int sd = t >> 3, sseg = t & 7;
    const bf16* kg_t = Kg + t * 8;                                    // + ch*2048
    const bf16* vg_t = Vg + (size_t)sd * SEQ + (sseg ^ (sd & 7)) * 8; // + ch*64
    char* kl = (char*)&Kb[0][0] + w * 1024;   // + buf*4096
    char* vl = (char*)&Vb[0][0] + w * 1024;

    // fragment read offsets
    const int kperm = 8 * (c >> 2) + (c & 3);
    const int kro = kperm * 64 + g * 16;      // byte offset within buffer
    const int cx = c & 7;
    const int vro0 = c * 128, vro1 = (16 + c) * 128;
    const int voffA = ((g) ^ cx) << 4;        // keys 0..31 V columns
    const int voffB = (((4 + g)) ^ cx) << 4;  // keys 32..63 V columns

    const f32x4 zf = {0.f, 0.f, 0.f, 0.f};
    union { uint32_t u[4]; bf16x8 v; } onesf;
    onesf.u[0] = onesf.u[1] = onesf.u[2] = onesf.u[3] = 0x3F803F80u;

    f32x4 o0 = zf, o1 = zf, ol = zf;

    // prologue: stage chunk 0
    gld_lds16(kg_t, kl);
    gld_lds16(vg_t, vl);
    __syncthreads();

    #pragma unroll 1
    for (int s = 0; s < nsteps; ++s) {
        // (1) issue async DMA for chunk s+1 into the other buffer
        const int sn = s + 1;
        if (sn < nsteps) {
            const int bo = (sn & 1) * 4096;
            gld_lds16(kg_t + (size_t)sn * 2048, kl + bo);
            gld_lds16(vg_t + (size_t)sn * 64, vl + bo);
        }
        // (2) compute chunk s from buf[s&1]
        const char* kbuf = (const char*)&Kb[s & 1][0];
        const char* vbuf = (const char*)&Vb[s & 1][0];
        const bool diag = (s == TT);
        const int qoff = w * 16 + c;

        // ---- keys 0..31 ----
        {
            bf16x8 kf0 = *(const bf16x8*)(kbuf + kro);
            bf16x8 kf1 = *(const bf16x8*)(kbuf + kro + 256);
            f32x4 st0 = __builtin_amdgcn_mfma_f32_16x16x32_bf16(kf0, qf, zf, 0, 0, 0);
            f32x4 st1 = __builtin_amdgcn_mfma_f32_16x16x32_bf16(kf1, qf, zf, 0, 0, 0);
            if (diag) {
                #pragma unroll
                for (int r = 0; r < 4; ++r) {
                    if (8 * g + r > qoff)     st0[r] = -1e30f;
                    if (8 * g + 4 + r > qoff) st1[r] = -1e30f;
                }
            }
            float p0 = fexp2(st0[0]), p1 = fexp2(st0[1]), p2 = fexp2(st0[2]), p3 = fexp2(st0[3]);
            float p4 = fexp2(st1[0]), p5 = fexp2(st1[1]), p6 = fexp2(st1[2]), p7 = fexp2(st1[3]);
            union { uint32_t u[4]; bf16x8 v; } pb;
            asm("v_cvt_pk_bf16_f32 %0, %1, %2" : "=v"(pb.u[0]) : "v"(p0), "v"(p1));
            asm("v_cvt_pk_bf16_f32 %0, %1, %2" : "=v"(pb.u[1]) : "v"(p2), "v"(p3));
            asm("v_cvt_pk_bf16_f32 %0, %1, %2" : "=v"(pb.u[2]) : "v"(p4), "v"(p5));
            asm("v_cvt_pk_bf16_f32 %0, %1, %2" : "=v"(pb.u[3]) : "v"(p6), "v"(p7));
            bf16x8 vfA = *(const bf16x8*)(vbuf + vro0 + voffA);
            bf16x8 vfB = *(const bf16x8*)(vbuf + vro1 + voffA);
            o0 = __builtin_amdgcn_mfma_f32_16x16x32_bf16(vfA, pb.v, o0, 0, 0, 0);
            o1 = __builtin_amdgcn_mfma_f32_16x16x32_bf16(vfB, pb.v, o1, 0, 0, 0);
            ol = __builtin_amdgcn_mfma_f32_16x16x32_bf16(onesf.v, pb.v, ol, 0, 0, 0);
        }
        // ---- keys 32..63 (on the diagonal step, waves 0-1 are fully masked) ----
        if (!diag || w >= 2) {
            bf16x8 kf2 = *(const bf16x8*)(kbuf + kro + 2048);
            bf16x8 kf3 = *(const bf16x8*)(kbuf + kro + 2304);
            f32x4 st2 = __builtin_amdgcn_mfma_f32_16x16x32_bf16(kf2, qf, zf, 0, 0, 0);
            f32x4 st3 = __builtin_amdgcn_mfma_f32_16x16x32_bf16(kf3, qf, zf, 0, 0, 0);
            if (diag) {
                #pragma unroll
                for (int r = 0; r < 4; ++r) {
                    if (32 + 8 * g + r > qoff)     st2[r] = -1e30f;
                    if (32 + 8 * g + 4 + r > qoff) st3[r] = -1e30f;
                }
            }
            float p0 = fexp2(st2[0]), p1 = fexp2(st2[1]), p2 = fexp2(st2[2]), p3 = fexp2(st2[3]);
            float p4 = fexp2(st3[0]), p5 = fexp2(st3[1]), p6 = fexp2(st3[2]), p7 = fexp2(st3[3]);
            union { uint32_t u[4]; bf16x8 v; } pb;
            asm("v_cvt_pk_bf16_f32 %0, %1, %2" : "=v"(pb.u[0]) : "v"(p0), "v"(p1));
            asm("v_cvt_pk_bf16_f32 %0, %1, %2" : "=v"(pb.u[1]) : "v"(p2), "v"(p3));
            asm("v_cvt_pk_bf16_f32 %0, %1, %2" : "=v"(pb.u[2]) : "v"(p4), "v"(p5));
            asm("v_cvt_pk_bf16_f32 %0, %1, %2" : "=v"(pb.u[3]) : "v"(p6), "v"(p7));
            bf16x8 vfA = *(const bf16x8*)(vbuf + vro0 + voffB);
            bf16x8 vfB = *(const bf16x8*)(vbuf + vro1 + voffB);
            o0 = __builtin_amdgcn_mfma_f32_16x16x32_bf16(vfA, pb.v, o0, 0, 0, 0);
            o1 = __builtin_amdgcn_mfma_f32_16x16x32_bf16(vfB, pb.v, o1, 0, 0, 0);
            ol = __builtin_amdgcn_mfma_f32_16x16x32_bf16(onesf.v, pb.v, ol, 0, 0, 0);
        }
        // (3) barrier: drains DMA (vmcnt 0) + orders LDS buffer reuse
        __syncthreads();
    }

    // epilogue (per-wave private tr slice -> no barrier needed)
    {
        float inv = 1.0f / ol[0];
        #pragma unroll
        for (int r = 0; r < 4; ++r) {
            tr[w][c * 33 + 4 * g + r]      = o0[r] * inv;   // O^T: (q=c, d)
            tr[w][c * 33 + 16 + 4 * g + r] = o1[r] * inv;
        }
        int q = lane >> 2, dp = (lane & 3) * 8;
        uint32_t u0 = pack_bf16(tr[w][q * 33 + dp + 0], tr[w][q * 33 + dp + 1]);
        uint32_t u1 = pack_bf16(tr[w][q * 33 + dp + 2], tr[w][q * 33 + dp + 3]);
        uint32_t u2 = pack_bf16(tr[w][q * 33 + dp + 4], tr[w][q * 33 + dp + 5]);
        uint32_t u3 = pack_bf16(tr[w][q * 33 + dp + 6], tr[w][q * 33 + dp + 7]);
        size_t base = ((size_t)b * SEQ + q0 + q) * HID + h * HDIM + dp;
        *(uint4*)&att[base] = make_uint4(u0, u1, u2, u3);
    }
}

// ---------------------------------------------------------------------------
// Kernel 3: output projection (unchanged).
// ---------------------------------------------------------------------------
__global__ __launch_bounds__(256) void out_proj(
    const bf16* __restrict__ att, const float* __restrict__ Wo,
    float* __restrict__ out)
{
    __shared__ bf16 As[64][136];
    __shared__ bf16 Bs[64][136];
    const int t = threadIdx.x;
    const int wid = t >> 6, lane = t & 63;
    const int g = lane >> 4, c = lane & 15;
    const int n0 = blockIdx.x * 64;
    const int m0 = blockIdx.y * 64;

    const f32x4 zf = {0.f, 0.f, 0.f, 0.f};
    f32x4 acc[4] = {zf, zf, zf, zf};

    const int c4 = t & 31;
    const int rb = t >> 5;

    for (int ks = 0; ks < 256; ks += 128) {
        __syncthreads();
        #pragma unroll
        for (int i = 0; i < 8; ++i) {
            int row = i * 8 + rb;
            ushort4 v = *(const ushort4*)&att[(size_t)(m0 + row) * HID + ks + c4 * 4];
            *(ushort4*)&As[row][c4 * 4] = v;
        }
        #pragma unroll
        for (int i = 0; i < 8; ++i) {
            int row = i * 8 + rb;
            float4 v = *(const float4*)&Wo[(size_t)(n0 + row) * HID + ks + c4 * 4];
            ushort4 w; w.x = bfbits(v.x); w.y = bfbits(v.y); w.z = bfbits(v.z); w.w = bfbits(v.w);
            *(ushort4*)&Bs[row][c4 * 4] = w;
        }
        __syncthreads();
        #pragma unroll
        for (int kk = 0; kk < 128; kk += 32) {
            bf16x8 af = *(const bf16x8*)&As[wid * 16 + c][kk + g * 8];
            #pragma unroll
            for (int nt = 0; nt < 4; ++nt) {
                bf16x8 bfr = *(const bf16x8*)&Bs[nt * 16 + c][kk + g * 8];
                acc[nt] = __builtin_amdgcn_mfma_f32_16x16x32_bf16(af, bfr, acc[nt], 0, 0, 0);
            }
        }
    }

    #pragma unroll
    for (int nt = 0; nt < 4; ++nt) {
        #pragma unroll
        for (int r = 0; r < 4; ++r) {
            int m = m0 + wid * 16 + g * 4 + r;
            out[(size_t)m * HID + n0 + nt * 16 + c] = acc[nt][r];
        }
    }
}

extern "C" void kernel_launch(void* const* d_in, const int* in_sizes, int n_in,
                              void* d_out, int out_size, void* d_ws, size_t ws_size,
                              hipStream_t stream) {
    const float* hs = (const float*)d_in[0];
    const float* Wq = (const float*)d_in[1];
    const float* Wk = (const float*)d_in[2];
    const float* Wv = (const float*)d_in[3];
    const float* Wo = (const float*)d_in[4];
    char* ws = (char*)d_ws;
    bf16* qws  = (bf16*)(ws);                 // [2][8][4096][32]  4,194,304 B
    bf16* kws  = (bf16*)(ws + 4194304);       // [2][4][4096][32]  2,097,152 B
    bf16* vtws = (bf16*)(ws + 6291456);       // [2][4][32][4096]  2,097,152 B
    bf16* att  = (bf16*)(ws + 8388608);       // [2][4096][256]    4,194,304 B

    qkv_proj<<<dim3(8, 128), 256, 0, stream>>>(hs, Wq, Wk, Wv, qws, kws, vtws);
    attn_fwd<<<1024, 256, 0, stream>>>(qws, kws, vtws, att);
    out_proj<<<dim3(4, 128), 256, 0, stream>>>(att, Wo, (float*)d_out);
}